// Round 1
// baseline (934.913 us; speedup 1.0000x reference)
//
#include <hip/hip_runtime.h>
#include <math.h>

#define B_SZ 8192
#define KD   256
#define NCLS 32
#define TM   64
#define TN   64
#define KC   32
#define INV_T 10.0f

// ---------------- kernel 1: reciprocal row norms ----------------
__global__ void rnorm_kernel(const float* __restrict__ feat, float* __restrict__ rnorm) {
    int row  = blockIdx.x * 4 + (threadIdx.x >> 6);   // 4 waves per block, 1 row each
    int lane = threadIdx.x & 63;
    const float4 v = ((const float4*)(feat + (size_t)row * KD))[lane]; // 64 lanes x 4 = 256
    float s = v.x * v.x + v.y * v.y + v.z * v.z + v.w * v.w;
    #pragma unroll
    for (int off = 32; off > 0; off >>= 1) s += __shfl_down(s, off, 64);
    if (lane == 0) rnorm[row] = 1.0f / sqrtf(s);
}

// ---------------- kernel 2: global per-class counts ----------------
__global__ void count_kernel(const int* __restrict__ labels, int* __restrict__ counts) {
    __shared__ int sc[NCLS];
    int t = threadIdx.x;
    if (t < NCLS) sc[t] = 0;
    __syncthreads();
    for (int i = t; i < B_SZ; i += 256) atomicAdd(&sc[labels[i]], 1);
    __syncthreads();
    if (t < NCLS) counts[t] = sc[t];
}

// ---------------- kernel 3: fused sim-GEMM + exp + class scatter ----------------
// grid: (nchunk, B/TM), block: 256 threads (16x16), 4x4 micro-tile per thread.
__global__ __launch_bounds__(256) void sim_kernel(
    const float* __restrict__ feat, const int* __restrict__ labels,
    const float* __restrict__ rnorm,
    float* __restrict__ pcls, float* __restrict__ ppos, int nchunk)
{
    __shared__ float sA[KC][TM];      // k-major (transposed) A tile
    __shared__ float sB[KC][TN];      // k-major (transposed) B tile
    __shared__ float scls[TM][NCLS];  // per-anchor per-class exp-sums
    __shared__ float spos[TM];        // per-anchor positive sim-sums

    const int chunk  = blockIdx.x;
    const int itile  = blockIdx.y;
    const int i0     = itile * TM;
    const int jchunk = B_SZ / nchunk;
    const int jbeg   = chunk * jchunk;
    const int t  = threadIdx.x;
    const int tx = t & 15;
    const int ty = t >> 4;

    for (int s = t; s < TM * NCLS; s += 256) ((float*)scls)[s] = 0.0f;
    if (t < TM) spos[t] = 0.0f;

    float rni[4]; int labi[4];
    #pragma unroll
    for (int mi = 0; mi < 4; mi++) {
        int i = i0 + ty * 4 + mi;
        rni[mi]  = rnorm[i];
        labi[mi] = labels[i];
    }
    __syncthreads();

    const int njt = jchunk / TN;
    for (int jt = 0; jt < njt; jt++) {
        const int j0 = jbeg + jt * TN;
        float acc[4][4];
        #pragma unroll
        for (int mi = 0; mi < 4; mi++)
            #pragma unroll
            for (int ni = 0; ni < 4; ni++) acc[mi][ni] = 0.0f;

        for (int kc = 0; kc < KD; kc += KC) {
            // stage A (64x32) and B (64x32) transposed into LDS; 2 float4 each per thread
            #pragma unroll
            for (int q = 0; q < 2; q++) {
                int vv = t + q * 256;
                int r  = vv >> 3;           // 0..63 row within tile
                int c  = (vv & 7) << 2;     // 0,4,...,28 col within k-chunk
                float4 a = *(const float4*)&feat[(size_t)(i0 + r) * KD + kc + c];
                sA[c + 0][r] = a.x; sA[c + 1][r] = a.y; sA[c + 2][r] = a.z; sA[c + 3][r] = a.w;
                float4 b = *(const float4*)&feat[(size_t)(j0 + r) * KD + kc + c];
                sB[c + 0][r] = b.x; sB[c + 1][r] = b.y; sB[c + 2][r] = b.z; sB[c + 3][r] = b.w;
            }
            __syncthreads();
            #pragma unroll
            for (int kk = 0; kk < KC; kk++) {
                float4 av = *(const float4*)&sA[kk][ty * 4];
                float4 bv = *(const float4*)&sB[kk][tx * 4];
                float am[4] = {av.x, av.y, av.z, av.w};
                float bm[4] = {bv.x, bv.y, bv.z, bv.w};
                #pragma unroll
                for (int mi = 0; mi < 4; mi++)
                    #pragma unroll
                    for (int ni = 0; ni < 4; ni++)
                        acc[mi][ni] = fmaf(am[mi], bm[ni], acc[mi][ni]);
            }
            __syncthreads();
        }

        // epilogue: scale -> exp -> scatter into LDS class sums
        float rnj[4]; int labj[4];
        #pragma unroll
        for (int ni = 0; ni < 4; ni++) {
            int j = j0 + tx * 4 + ni;
            rnj[ni]  = rnorm[j];
            labj[ni] = labels[j];
        }
        #pragma unroll
        for (int mi = 0; mi < 4; mi++) {
            const int i = i0 + ty * 4 + mi;
            #pragma unroll
            for (int ni = 0; ni < 4; ni++) {
                const int j = j0 + tx * 4 + ni;
                if (i == j) continue;   // exclude self
                float sim = acc[mi][ni] * rni[mi] * rnj[ni] * INV_T;
                float e = expf(sim);
                atomicAdd(&scls[i - i0][labj[ni]], e);
                if (labj[ni] == labi[mi]) atomicAdd(&spos[i - i0], sim);
            }
        }
    }
    __syncthreads();

    const int bid = itile * nchunk + chunk;
    float* pc = pcls + (size_t)bid * TM * NCLS;
    for (int s = t; s < TM * NCLS; s += 256) pc[s] = ((float*)scls)[s];
    if (t < TM) ppos[(size_t)bid * TM + t] = spos[t];
}

// ---------------- kernel 4: per-anchor loss ----------------
__global__ void reduce_kernel(const float* __restrict__ pcls, const float* __restrict__ ppos,
                              const int* __restrict__ counts, const int* __restrict__ labels,
                              float* __restrict__ loss_i, float* __restrict__ validf, int nchunk) {
    int i = blockIdx.x * blockDim.x + threadIdx.x;
    if (i >= B_SZ) return;
    int itile = i >> 6, ilocal = i & 63;
    float csum[NCLS];
    #pragma unroll
    for (int c = 0; c < NCLS; c++) csum[c] = 0.0f;
    float psum = 0.0f;
    for (int ch = 0; ch < nchunk; ch++) {
        int bid = itile * nchunk + ch;
        const float* p = pcls + (size_t)bid * TM * NCLS + (size_t)ilocal * NCLS;
        #pragma unroll
        for (int c = 0; c < NCLS; c++) csum[c] += p[c];
        psum += ppos[(size_t)bid * TM + ilocal];
    }
    int labi = labels[i];
    float denom = 0.0f;
    #pragma unroll
    for (int c = 0; c < NCLS; c++) {
        int cnt = counts[c] - (c == labi ? 1 : 0);
        if (cnt > 0) denom += csum[c] / (float)cnt;
    }
    int P = counts[labi] - 1;
    bool valid = P > 0;
    float li = 0.0f;
    if (valid) li = logf(fmaxf(denom, 1e-30f)) - psum / (float)max(P, 1);
    loss_i[i] = li;
    validf[i] = valid ? 1.0f : 0.0f;
}

// ---------------- kernel 5: deterministic final reduction ----------------
__global__ void final_kernel(const float* __restrict__ loss_i, const float* __restrict__ validf,
                             float* __restrict__ out) {
    __shared__ float ssum[256];
    __shared__ float scnt[256];
    int t = threadIdx.x;
    float s = 0.0f, c = 0.0f;
    for (int i = t; i < B_SZ; i += 256) { s += loss_i[i]; c += validf[i]; }
    ssum[t] = s; scnt[t] = c;
    __syncthreads();
    #pragma unroll
    for (int off = 128; off > 0; off >>= 1) {
        if (t < off) { ssum[t] += ssum[t + off]; scnt[t] += scnt[t + off]; }
        __syncthreads();
    }
    if (t == 0) out[0] = (scnt[0] > 0.0f) ? ssum[0] / scnt[0] : 0.0f;
}

// ---------------- launch ----------------
extern "C" void kernel_launch(void* const* d_in, const int* in_sizes, int n_in,
                              void* d_out, int out_size, void* d_ws, size_t ws_size,
                              hipStream_t stream) {
    const float* feat   = (const float*)d_in[0];
    const int*   labels = (const int*)d_in[1];
    float*       out    = (float*)d_out;

    char* ws = (char*)d_ws;
    size_t off = 0;
    auto alloc = [&](size_t bytes) -> void* {
        void* p = ws + off;
        off = (off + bytes + 255) & ~(size_t)255;
        return p;
    };

    float* rnorm  = (float*)alloc((size_t)B_SZ * 4);
    int*   counts = (int*)alloc((size_t)NCLS * 4);
    float* loss_i = (float*)alloc((size_t)B_SZ * 4);
    float* validf = (float*)alloc((size_t)B_SZ * 4);

    // split j-dim into nchunk pieces for grid occupancy; shrink if ws too small
    int nchunk = 8;
    while (nchunk > 1 &&
           off + (size_t)nchunk * B_SZ * 4 + (size_t)nchunk * B_SZ * NCLS * 4 + 2048 > ws_size)
        nchunk >>= 1;
    float* ppos = (float*)alloc((size_t)nchunk * B_SZ * 4);
    float* pcls = (float*)alloc((size_t)nchunk * B_SZ * NCLS * 4);

    rnorm_kernel<<<B_SZ / 4, 256, 0, stream>>>(feat, rnorm);
    count_kernel<<<1, 256, 0, stream>>>(labels, counts);
    sim_kernel<<<dim3(nchunk, B_SZ / TM), 256, 0, stream>>>(feat, labels, rnorm, pcls, ppos, nchunk);
    reduce_kernel<<<B_SZ / 256, 256, 0, stream>>>(pcls, ppos, counts, labels, loss_i, validf, nchunk);
    final_kernel<<<1, 256, 0, stream>>>(loss_i, validf, out);
}

// Round 2
// 494.133 us; speedup vs baseline: 1.8920x; 1.8920x over previous
//
#include <hip/hip_runtime.h>
#include <math.h>

#define B_SZ 8192
#define KD   256
#define NCLS 32
#define INV_T 10.0f

typedef __attribute__((ext_vector_type(8))) short short8;
typedef __attribute__((ext_vector_type(4))) float f32x4;

static __device__ __forceinline__ unsigned short f2bf(float f) {
    unsigned u = __float_as_uint(f);
    unsigned r = (u + 0x7FFF + ((u >> 16) & 1)) >> 16;   // RNE
    return (unsigned short)r;
}

// ---------------- kernel 1: normalize rows, split into bf16 hi/lo ----------------
__global__ void prep_kernel(const float* __restrict__ feat,
                            unsigned short* __restrict__ fhi,
                            unsigned short* __restrict__ flo) {
    int row  = blockIdx.x * 4 + (threadIdx.x >> 6);
    int lane = threadIdx.x & 63;
    const float4 v = ((const float4*)(feat + (size_t)row * KD))[lane];
    float s = v.x * v.x + v.y * v.y + v.z * v.z + v.w * v.w;
    #pragma unroll
    for (int off = 1; off < 64; off <<= 1) s += __shfl_xor(s, off, 64);
    float rn = rsqrtf(s);
    float fn[4] = {v.x * rn, v.y * rn, v.z * rn, v.w * rn};
    ushort4 hi, lo;
    unsigned short* hp = (unsigned short*)&hi;
    unsigned short* lp = (unsigned short*)&lo;
    #pragma unroll
    for (int e = 0; e < 4; e++) {
        unsigned short h = f2bf(fn[e]);
        float hf = __uint_as_float((unsigned)h << 16);
        hp[e] = h;
        lp[e] = f2bf(fn[e] - hf);
    }
    ((ushort4*)(fhi + (size_t)row * KD))[lane] = hi;
    ((ushort4*)(flo + (size_t)row * KD))[lane] = lo;
}

// ---------------- kernel 2: global per-class counts ----------------
__global__ void count_kernel(const int* __restrict__ labels, int* __restrict__ counts) {
    __shared__ int sc[NCLS];
    int t = threadIdx.x;
    if (t < NCLS) sc[t] = 0;
    __syncthreads();
    for (int i = t; i < B_SZ; i += 256) atomicAdd(&sc[labels[i]], 1);
    __syncthreads();
    if (t < NCLS) counts[t] = sc[t];
}

// ---------------- kernel 3: bf16-split MFMA sim-GEMM + exp + class scatter ----------------
// grid: (nchunk, 64). 128x128 C-tile per block, 4 waves in 2x2, 64x64 per wave.
// BK=64, LDS tiles [128 rows][64 bf16] with slot-XOR swizzle (both sides).
__global__ __launch_bounds__(256) void sim_kernel(
    const unsigned short* __restrict__ fhi, const unsigned short* __restrict__ flo,
    const int* __restrict__ labels,
    float* __restrict__ pcls, float* __restrict__ ppos, int nchunk)
{
    __shared__ __align__(16) unsigned short sA[128 * 64];  // 16KB
    __shared__ __align__(16) unsigned short sB[128 * 64];  // 16KB
    __shared__ float scls[128][NCLS + 1];                  // padded vs bank conflict
    __shared__ float spos[128];

    const int t    = threadIdx.x;
    const int wave = t >> 6;
    const int lane = t & 63;
    const int wr   = wave >> 1;      // wave row (0/1) -> 64 rows
    const int wc   = wave & 1;       // wave col (0/1) -> 64 cols
    const int l15  = lane & 15;
    const int l4   = lane >> 4;
    const int i0   = blockIdx.y * 128;
    const int jtpc = 64 / nchunk;    // j-tiles (of 128) per chunk
    const int jt0  = blockIdx.x * jtpc;

    for (int s = t; s < 128 * (NCLS + 1); s += 256) ((float*)scls)[s] = 0.0f;
    if (t < 128) spos[t] = 0.0f;

    // anchor labels for this lane's 16 C-rows
    int labi[4][4];
    #pragma unroll
    for (int m = 0; m < 4; m++)
        #pragma unroll
        for (int q = 0; q < 4; q++)
            labi[m][q] = labels[i0 + wr * 64 + m * 16 + l4 * 4 + q];

    // staging address components (per issue a: rows a*32 + t/8, slot t&7)
    const int rL = t >> 3;        // row-within-32 covered by this thread
    const int s8 = t & 7;         // physical 16B slot this thread's data lands in

    for (int jt = jt0; jt < jt0 + jtpc; ++jt) {
        const int j0 = jt * 128;
        f32x4 acc[4][4];
        #pragma unroll
        for (int m = 0; m < 4; m++)
            #pragma unroll
            for (int n = 0; n < 4; n++)
                acc[m][n] = (f32x4){0.f, 0.f, 0.f, 0.f};

        #pragma unroll 1
        for (int pass = 0; pass < 3; ++pass) {
            const unsigned short* ap = (pass == 2) ? flo : fhi;
            const unsigned short* bp = (pass == 1) ? flo : fhi;
            #pragma unroll 1
            for (int kc = 0; kc < KD; kc += 64) {
                __syncthreads();   // previous compute done before overwriting LDS
                #pragma unroll
                for (int a = 0; a < 4; ++a) {
                    int r   = a * 32 + rL;
                    int ksw = (s8 ^ (r & 7)) * 8;   // pre-swizzled global source
                    const unsigned short* gA = ap + (size_t)(i0 + r) * KD + kc + ksw;
                    char* lA = (char*)sA + a * 4096 + wave * 1024;
                    __builtin_amdgcn_global_load_lds(
                        (const __attribute__((address_space(1))) void*)gA,
                        (__attribute__((address_space(3))) void*)lA, 16, 0, 0);
                    const unsigned short* gB = bp + (size_t)(j0 + r) * KD + kc + ksw;
                    char* lB = (char*)sB + a * 4096 + wave * 1024;
                    __builtin_amdgcn_global_load_lds(
                        (const __attribute__((address_space(1))) void*)gB,
                        (__attribute__((address_space(3))) void*)lB, 16, 0, 0);
                }
                __syncthreads();   // loads landed (compiler drains vmcnt before barrier)

                #pragma unroll
                for (int kk = 0; kk < 2; ++kk) {
                    short8 af[4], bf4[4];
                    #pragma unroll
                    for (int m = 0; m < 4; ++m) {
                        int r    = wr * 64 + m * 16 + l15;
                        int slog = kk * 4 + l4;
                        af[m] = *(const short8*)&sA[r * 64 + ((slog ^ (r & 7)) * 8)];
                    }
                    #pragma unroll
                    for (int n = 0; n < 4; ++n) {
                        int r    = wc * 64 + n * 16 + l15;
                        int slog = kk * 4 + l4;
                        bf4[n] = *(const short8*)&sB[r * 64 + ((slog ^ (r & 7)) * 8)];
                    }
                    #pragma unroll
                    for (int m = 0; m < 4; ++m)
                        #pragma unroll
                        for (int n = 0; n < 4; ++n)
                            acc[m][n] = __builtin_amdgcn_mfma_f32_16x16x32_bf16(
                                af[m], bf4[n], acc[m][n], 0, 0, 0);
                }
            }
        }

        // epilogue: scale -> exp -> scatter (C layout: col=lane&15, row=(lane>>4)*4+reg)
        int labj[4];
        #pragma unroll
        for (int n = 0; n < 4; ++n)
            labj[n] = labels[j0 + wc * 64 + n * 16 + l15];
        #pragma unroll
        for (int m = 0; m < 4; ++m) {
            #pragma unroll
            for (int n = 0; n < 4; ++n) {
                const int jg = j0 + wc * 64 + n * 16 + l15;
                #pragma unroll
                for (int q = 0; q < 4; ++q) {
                    const int il = wr * 64 + m * 16 + l4 * 4 + q;   // row within i-tile
                    const int ig = i0 + il;
                    if (ig == jg) continue;
                    float sim = acc[m][n][q] * INV_T;
                    float e = __expf(sim);
                    atomicAdd(&scls[il][labj[n]], e);
                    if (labj[n] == labi[m][q]) atomicAdd(&spos[il], sim);
                }
            }
        }
    }
    __syncthreads();

    const int bid = blockIdx.y * nchunk + blockIdx.x;
    float* pc = pcls + (size_t)bid * 128 * NCLS;
    for (int s = t; s < 128 * NCLS; s += 256) pc[s] = scls[s >> 5][s & 31];
    if (t < 128) ppos[(size_t)bid * 128 + t] = spos[t];
}

// ---------------- kernel 4: per-anchor loss ----------------
__global__ void reduce_kernel(const float* __restrict__ pcls, const float* __restrict__ ppos,
                              const int* __restrict__ counts, const int* __restrict__ labels,
                              float* __restrict__ loss_i, float* __restrict__ validf, int nchunk) {
    int i = blockIdx.x * blockDim.x + threadIdx.x;
    if (i >= B_SZ) return;
    int itile = i >> 7, ilocal = i & 127;
    float csum[NCLS];
    #pragma unroll
    for (int c = 0; c < NCLS; c++) csum[c] = 0.0f;
    float psum = 0.0f;
    for (int ch = 0; ch < nchunk; ch++) {
        int bid = itile * nchunk + ch;
        const float* p = pcls + (size_t)bid * 128 * NCLS + (size_t)ilocal * NCLS;
        #pragma unroll
        for (int c = 0; c < NCLS; c++) csum[c] += p[c];
        psum += ppos[(size_t)bid * 128 + ilocal];
    }
    int labi = labels[i];
    float denom = 0.0f;
    #pragma unroll
    for (int c = 0; c < NCLS; c++) {
        int cnt = counts[c] - (c == labi ? 1 : 0);
        if (cnt > 0) denom += csum[c] / (float)cnt;
    }
    int P = counts[labi] - 1;
    bool valid = P > 0;
    float li = 0.0f;
    if (valid) li = logf(fmaxf(denom, 1e-30f)) - psum / (float)max(P, 1);
    loss_i[i] = li;
    validf[i] = valid ? 1.0f : 0.0f;
}

// ---------------- kernel 5: deterministic final reduction ----------------
__global__ void final_kernel(const float* __restrict__ loss_i, const float* __restrict__ validf,
                             float* __restrict__ out) {
    __shared__ float ssum[256];
    __shared__ float scnt[256];
    int t = threadIdx.x;
    float s = 0.0f, c = 0.0f;
    for (int i = t; i < B_SZ; i += 256) { s += loss_i[i]; c += validf[i]; }
    ssum[t] = s; scnt[t] = c;
    __syncthreads();
    #pragma unroll
    for (int off = 128; off > 0; off >>= 1) {
        if (t < off) { ssum[t] += ssum[t + off]; scnt[t] += scnt[t + off]; }
        __syncthreads();
    }
    if (t == 0) out[0] = (scnt[0] > 0.0f) ? ssum[0] / scnt[0] : 0.0f;
}

// ---------------- launch ----------------
extern "C" void kernel_launch(void* const* d_in, const int* in_sizes, int n_in,
                              void* d_out, int out_size, void* d_ws, size_t ws_size,
                              hipStream_t stream) {
    const float* feat   = (const float*)d_in[0];
    const int*   labels = (const int*)d_in[1];
    float*       out    = (float*)d_out;

    char* ws = (char*)d_ws;
    size_t off = 0;
    auto alloc = [&](size_t bytes) -> void* {
        void* p = ws + off;
        off = (off + bytes + 255) & ~(size_t)255;
        return p;
    };

    unsigned short* fhi = (unsigned short*)alloc((size_t)B_SZ * KD * 2);
    unsigned short* flo = (unsigned short*)alloc((size_t)B_SZ * KD * 2);
    int*   counts = (int*)alloc((size_t)NCLS * 4);
    float* loss_i = (float*)alloc((size_t)B_SZ * 4);
    float* validf = (float*)alloc((size_t)B_SZ * 4);

    int nchunk = 8;   // j-dim split: grid = 64*nchunk blocks
    while (nchunk > 1 &&
           off + (size_t)64 * nchunk * 128 * 4 + (size_t)64 * nchunk * 128 * NCLS * 4 + 4096 > ws_size)
        nchunk >>= 1;
    float* ppos = (float*)alloc((size_t)64 * nchunk * 128 * 4);
    float* pcls = (float*)alloc((size_t)64 * nchunk * 128 * NCLS * 4);

    prep_kernel<<<B_SZ / 4, 256, 0, stream>>>(feat, fhi, flo);
    count_kernel<<<1, 256, 0, stream>>>(labels, counts);
    sim_kernel<<<dim3(nchunk, B_SZ / 128), 256, 0, stream>>>(fhi, flo, labels, pcls, ppos, nchunk);
    reduce_kernel<<<B_SZ / 256, 256, 0, stream>>>(pcls, ppos, counts, labels, loss_i, validf, nchunk);
    final_kernel<<<1, 256, 0, stream>>>(loss_i, validf, out);
}